// Round 2
// baseline (802.086 us; speedup 1.0000x reference)
//
#include <hip/hip_runtime.h>
#include <stdint.h>
#include <stddef.h>

// ---------------------------------------------------------------------------
// Round 4: deep-pipelined 256x256 GEMM, BK=32, 4-slot LDS ring.
// Counted vmcnt(12) in steady state -- 3 K-tiles (12 loads/thread) stay in
// flight ACROSS barriers; never drained in-loop (T3/T4). 64B LDS rows make
// ds_read_b128 fragment reads naturally bank-conflict-free (no swizzle).
// setprio around the MFMA cluster (T5), XCD-aware block swizzle (T1).
// Used 4x:  Et = X_t*Wt^T+bt   (f16 out, scratch in d_out)
//           El = X_l*Wl^T+bl   (f16 out, scratch in d_out)
//           V-GEMM + fused softmax-merge epilogue -> Mg (f16, ws)
//           final projection (fp32 out + bias)
// ---------------------------------------------------------------------------

typedef _Float16 h8 __attribute__((ext_vector_type(8)));
typedef _Float16 h4 __attribute__((ext_vector_type(4)));
typedef float    f4 __attribute__((ext_vector_type(4)));

#define NROWS 32768

__device__ __forceinline__ void async_ld16(const void* g, void* s) {
  __builtin_amdgcn_global_load_lds(
      (const __attribute__((address_space(1))) uint32_t*)g,
      (__attribute__((address_space(3))) uint32_t*)s, 16, 0, 0);
}

#define MEMFENCE asm volatile("" ::: "memory")

// Stage K-tile t into ring slot `slot`: A 256x32 halves (16KB) + B 256x32
// (16KB). 4 global_load_lds per thread. LDS dest linear (row*64B), lane's
// 16B lands at row = l*128 + w*16 + (lane>>2), chunk = (lane&3)*16B.
#define STAGE(slot, t)                                                        \
  {                                                                           \
    char* dA_ = smem + (slot) * 32768 + sdst;                                 \
    _Pragma("unroll") for (int l_ = 0; l_ < 2; ++l_) {                        \
      async_ld16(gA[l_] + (size_t)(t) * 32, dA_ + l_ * 8192);                 \
      async_ld16(gB[l_] + (size_t)(t) * 32, dA_ + 16384 + l_ * 8192);         \
    }                                                                         \
  }

// One K-tile phase: barrier (publish), 12x ds_read_b128, 32 MFMA, barrier.
#define PHASE(slot)                                                           \
  {                                                                           \
    __builtin_amdgcn_s_barrier();                                             \
    MEMFENCE;                                                                 \
    const char* As_ = smem + (slot) * 32768;                                  \
    h8 af[8], bf[4];                                                          \
    _Pragma("unroll") for (int i = 0; i < 8; ++i)                             \
        af[i] = *(const h8*)(As_ + aoff + i * 1024);                          \
    _Pragma("unroll") for (int j = 0; j < 4; ++j)                             \
        bf[j] = *(const h8*)(As_ + boff + j * 1024);                          \
    __builtin_amdgcn_s_setprio(1);                                            \
    _Pragma("unroll") for (int i = 0; i < 8; ++i)                             \
      _Pragma("unroll") for (int j = 0; j < 4; ++j)                           \
        acc[i][j] = __builtin_amdgcn_mfma_f32_16x16x32_f16(af[i], bf[j],      \
                                                           acc[i][j], 0, 0, 0); \
    __builtin_amdgcn_s_setprio(0);                                            \
    MEMFENCE;                                                                 \
    __builtin_amdgcn_s_barrier();                                             \
    MEMFENCE;                                                                 \
  }

// MODE: 0 = f16 out + bias; 1 = fused softmax-merge (reads Et/El, writes Mg);
//       2 = fp32 out + bias.
// Tile 256x256, 8 waves (2 row x 4 col), per-wave 128x64 output.
template<int NT, int MODE>
__launch_bounds__(512, 2)
__global__ void gemm256(const _Float16* __restrict__ A, int lda,
                        const _Float16* __restrict__ B, int ldb,
                        const float* __restrict__ bias,
                        const _Float16* __restrict__ Et,
                        const _Float16* __restrict__ El,
                        _Float16* __restrict__ C16,
                        float* __restrict__ C32) {
  __shared__ char smem[131072];   // 4 ring slots x (A 16KB + B 16KB)

  // XCD-aware swizzle: 64 consecutive row-blocks per XCD slot (512 % 8 == 0).
  const int b  = blockIdx.x;
  const int bp = ((b & 7) << 6) | (b >> 3);
  const int row0 = (bp & 127) << 8;
  const int col0 = (bp >> 7) << 8;

  const int tid  = threadIdx.x;
  const int w    = tid >> 6;
  const int lane = tid & 63;
  const int quad = lane >> 4;
  const int l16  = lane & 15;
  const int wr   = w >> 2;            // 0..1
  const int wc   = w & 3;             // 0..3

  // staging source addresses (k advances by t*32 halves per tile)
  const int srow = w * 16 + (lane >> 2);   // 0..127, +l*128
  const int schk = (lane & 3) * 8;         // halves
  const _Float16* gA[2];
  const _Float16* gB[2];
#pragma unroll
  for (int l = 0; l < 2; ++l) {
    gA[l] = A + (size_t)(row0 + l * 128 + srow) * (size_t)lda + schk;
    gB[l] = B + (size_t)(col0 + l * 128 + srow) * (size_t)ldb + schk;
  }
  const int sdst = w * 1024;   // + lane*16 implicit in global_load_lds

  // fragment read byte offsets (rows 64B; conflict-free: bank group
  // = 16*(row&1) + 4*quad covers all 32 banks uniformly at the 8/bank floor)
  const uint32_t aoff = (uint32_t)((wr * 128 + l16) * 64 + quad * 16);
  const uint32_t boff = (uint32_t)(16384 + (wc * 64 + l16) * 64 + quad * 16);

  f4 acc[8][4];
  const f4 z = {0.f, 0.f, 0.f, 0.f};
#pragma unroll
  for (int i = 0; i < 8; ++i)
#pragma unroll
    for (int j = 0; j < 4; ++j) acc[i][j] = z;

  // prologue: fill ring slots 0..2 (12 loads in flight)
  STAGE(0, 0);
  STAGE(1, 1);
  STAGE(2, 2);

  // steady state: stage t+3, keep 12 loads (3 tiles) in flight across the
  // barrier; wait only for tile t's own 4 loads.
  for (int t = 0; t < NT - 3; ++t) {
    STAGE((t + 3) & 3, t + 3);
    asm volatile("s_waitcnt vmcnt(12)" ::: "memory");
    PHASE(t & 3);
  }
  // tail: drain 8 -> 4 -> 0
  asm volatile("s_waitcnt vmcnt(8)" ::: "memory");
  PHASE((NT - 3) & 3);
  asm volatile("s_waitcnt vmcnt(4)" ::: "memory");
  PHASE((NT - 2) & 3);
  asm volatile("s_waitcnt vmcnt(0)" ::: "memory");
  PHASE((NT - 1) & 3);

  // ---- epilogue ----
  // C frag layout: col = l16, row = quad*4 + r
  const int cbase  = col0 + (wc << 6);
  const int rbase0 = row0 + (wr << 7) + (quad << 2);

  if constexpr (MODE == 0) {
    float bj[4];
#pragma unroll
    for (int j = 0; j < 4; ++j) bj[j] = bias[cbase + j * 16 + l16];
#pragma unroll
    for (int i = 0; i < 8; ++i)
#pragma unroll
      for (int j = 0; j < 4; ++j) {
        const size_t co = (size_t)(cbase + j * 16 + l16);
#pragma unroll
        for (int r = 0; r < 4; ++r)
          C16[(size_t)(rbase0 + i * 16 + r) * 1024 + co] =
              (_Float16)(acc[i][j][r] + bj[j]);
      }
  } else if constexpr (MODE == 2) {
    float bj[4];
#pragma unroll
    for (int j = 0; j < 4; ++j) bj[j] = bias[cbase + j * 16 + l16];
#pragma unroll
    for (int i = 0; i < 8; ++i)
#pragma unroll
      for (int j = 0; j < 4; ++j) {
        const size_t co = (size_t)(cbase + j * 16 + l16);
#pragma unroll
        for (int r = 0; r < 4; ++r)
          C32[(size_t)(rbase0 + i * 16 + r) * 1024 + co] = acc[i][j][r] + bj[j];
      }
  } else {
    // fused softmax-merge: wave's 64 cols == exactly one head group.
    float bvj[4];
#pragma unroll
    for (int j = 0; j < 4; ++j) bvj[j] = bias[cbase + j * 16 + l16];
#pragma unroll
    for (int i = 0; i < 8; ++i) {
      float pv[4][4];
      float s[4] = {0.f, 0.f, 0.f, 0.f};
      const int rb = rbase0 + i * 16;
#pragma unroll
      for (int j = 0; j < 4; ++j) {
        const size_t co = (size_t)(cbase + j * 16 + l16);
#pragma unroll
        for (int r = 0; r < 4; ++r) {
          const size_t off = (size_t)(rb + r) * 1024 + co;
          const float tv = (float)Et[off];   // bias already folded in
          const float lv = (float)El[off];
          const float p  = __expf(tv * lv);
          pv[j][r] = p * (acc[i][j][r] + bvj[j]);
          s[r] += p;
        }
      }
#pragma unroll
      for (int r = 0; r < 4; ++r) {
        s[r] += __shfl_xor(s[r], 1);
        s[r] += __shfl_xor(s[r], 2);
        s[r] += __shfl_xor(s[r], 4);
        s[r] += __shfl_xor(s[r], 8);
        s[r] = 1.0f / s[r];
      }
#pragma unroll
      for (int j = 0; j < 4; ++j) {
        const size_t co = (size_t)(cbase + j * 16 + l16);
#pragma unroll
        for (int r = 0; r < 4; ++r)
          C16[(size_t)(rb + r) * 1024 + co] = (_Float16)(pv[j][r] * s[r]);
      }
    }
  }
}

// ---------------------------------------------------------------------------
// Prep kernels (unchanged)
// ---------------------------------------------------------------------------
__global__ void cvt_inputs(const float4* __restrict__ t,
                           const float4* __restrict__ l,
                           h4* __restrict__ X) {
  const size_t idx = (size_t)blockIdx.x * 256 + threadIdx.x;  // N*1024/4
  const size_t n  = idx >> 8;
  const size_t k4 = idx & 255;
  const float4 a = t[idx];
  const float4 b = l[idx];
  h4 ha, hb;
  ha[0] = (_Float16)a.x; ha[1] = (_Float16)a.y;
  ha[2] = (_Float16)a.z; ha[3] = (_Float16)a.w;
  hb[0] = (_Float16)b.x; hb[1] = (_Float16)b.y;
  hb[2] = (_Float16)b.z; hb[3] = (_Float16)b.w;
  X[n * 512 + k4]       = ha;
  X[n * 512 + 256 + k4] = hb;
}

__global__ void cvt_flat(const float4* __restrict__ W, h4* __restrict__ Wp) {
  const int idx = blockIdx.x * 256 + threadIdx.x;
  const float4 v = W[idx];
  h4 hv;
  hv[0] = (_Float16)v.x; hv[1] = (_Float16)v.y;
  hv[2] = (_Float16)v.z; hv[3] = (_Float16)v.w;
  Wp[idx] = hv;
}

// Wo with K-dim permuted to match Mg's column order c = h*64+o
__global__ void cvt_wo_perm(const float* __restrict__ Wo,
                            _Float16* __restrict__ Wp) {
  const int idx = blockIdx.x * 256 + threadIdx.x;  // 1M
  const int j = idx >> 10, c = idx & 1023;
  const int k = (c & 63) * 16 + (c >> 6);
  Wp[idx] = (_Float16)Wo[j * 1024 + k];
}

// ---------------------------------------------------------------------------
// Launch. ws (~212 MB):  X16 134MB | Wt16 2MB | Wl16 2MB | Wv16 4MB |
//                        Wo16 2MB  | Mg 67MB
// d_out doubles as f16 scratch for Et/El (2 x 67MB = exactly out_size);
// consumed by the V kernel before the final GEMM overwrites d_out.
// ---------------------------------------------------------------------------
extern "C" void kernel_launch(void* const* d_in, const int* in_sizes, int n_in,
                              void* d_out, int out_size, void* d_ws, size_t ws_size,
                              hipStream_t stream) {
  const float* t_inp = (const float*)d_in[0];
  const float* l_inp = (const float*)d_in[1];
  const float* Wt = (const float*)d_in[2];
  const float* bt = (const float*)d_in[3];
  const float* Wl = (const float*)d_in[4];
  const float* bl = (const float*)d_in[5];
  const float* Wv = (const float*)d_in[6];
  const float* bv = (const float*)d_in[7];
  const float* Wo = (const float*)d_in[8];
  const float* bo = (const float*)d_in[9];
  float* out = (float*)d_out;

  char* ws = (char*)d_ws;
  _Float16* X16  = (_Float16*)ws;
  _Float16* Wt16 = (_Float16*)(ws + 134217728ull);
  _Float16* Wl16 = Wt16 + 1024 * 1024;
  _Float16* Wv16 = Wl16 + 1024 * 1024;
  _Float16* Wo16 = Wv16 + 1024 * 2048;
  _Float16* Mg   = Wo16 + 1024 * 1024;

  _Float16* Et16 = (_Float16*)d_out;            // scratch: 67MB
  _Float16* El16 = Et16 + (size_t)NROWS * 1024; // scratch: 67MB

  cvt_inputs<<<dim3(32768), dim3(256), 0, stream>>>(
      (const float4*)t_inp, (const float4*)l_inp, (h4*)X16);
  cvt_flat<<<dim3(1024), dim3(256), 0, stream>>>((const float4*)Wt, (h4*)Wt16);
  cvt_flat<<<dim3(1024), dim3(256), 0, stream>>>((const float4*)Wl, (h4*)Wl16);
  cvt_flat<<<dim3(2048), dim3(256), 0, stream>>>((const float4*)Wv, (h4*)Wv16);
  cvt_wo_perm<<<dim3(4096), dim3(256), 0, stream>>>(Wo, Wo16);

  // Et = X_t * Wt^T + bt   (f16, into d_out scratch)   K=1024 -> NT=32
  gemm256<32, 0><<<dim3(512), dim3(512), 0, stream>>>(
      X16, 2048, Wt16, 1024, bt, nullptr, nullptr, Et16, nullptr);
  // El = X_l * Wl^T + bl
  gemm256<32, 0><<<dim3(512), dim3(512), 0, stream>>>(
      X16 + 1024, 2048, Wl16, 1024, bl, nullptr, nullptr, El16, nullptr);
  // V GEMM + fused softmax-merge -> Mg                 K=2048 -> NT=64
  gemm256<64, 1><<<dim3(512), dim3(512), 0, stream>>>(
      X16, 2048, Wv16, 2048, bv, Et16, El16, Mg, nullptr);
  // final projection (fp32 out + bias)                 K=1024 -> NT=32
  gemm256<32, 2><<<dim3(512), dim3(512), 0, stream>>>(
      Mg, 1024, Wo16, 1024, bo, nullptr, nullptr, nullptr, out);
}

// Round 3
// 749.183 us; speedup vs baseline: 1.0706x; 1.0706x over previous
//
#include <hip/hip_runtime.h>
#include <stdint.h>
#include <stddef.h>

// ---------------------------------------------------------------------------
// Round 5: true 8-phase schedule (m201-style) on the round-1 conflict-free
// LDS layout (128B rows + 3-bit XOR swizzle; measured 0 bank conflicts).
// Per K-tile (BK=64), 4 phases of {ds_read subtile + stage 1 half-tile +
// barrier + 16 MFMA + barrier}. bf (both k-halves) front-loaded in phase 0
// so B-half slots free early; stage stream A-h0(t+1), A-h1(t+1), B-h0(t+2),
// B-h1(t+2) with ONE vmcnt(4) per K-tile -- 2 half-tiles always in flight,
// never drained in-loop. setprio around MFMA clusters, XCD block swizzle.
// Used 4x:  Et = X_t*Wt^T+bt   (f16 out, scratch in d_out)
//           El = X_l*Wl^T+bl   (f16 out, scratch in d_out)
//           V-GEMM + fused softmax-merge epilogue -> Mg (f16, ws)
//           final projection (fp32 out + bias)
// ---------------------------------------------------------------------------

typedef _Float16 h8 __attribute__((ext_vector_type(8)));
typedef _Float16 h4 __attribute__((ext_vector_type(4)));
typedef float    f4 __attribute__((ext_vector_type(4)));

#define NROWS 32768

__device__ __forceinline__ void async_ld16(const void* g, void* s) {
  __builtin_amdgcn_global_load_lds(
      (const __attribute__((address_space(1))) uint32_t*)g,
      (__attribute__((address_space(3))) uint32_t*)s, 16, 0, 0);
}

#define MEMFENCE asm volatile("" ::: "memory")

// Stage one A half-tile (rows hh*128..+127, K-tile t) into buffer at bufb.
#define STAGE_A(hh, t, bufb)                                                  \
  {                                                                           \
    _Pragma("unroll") for (int q_ = 0; q_ < 2; ++q_)                          \
        async_ld16(pA[hh][q_] + (size_t)(t) * 64,                             \
                   smem + (bufb) + (hh) * 16384 + q_ * 8192 + woff);          \
  }
#define STAGE_B(hh, t, bufb)                                                  \
  {                                                                           \
    _Pragma("unroll") for (int q_ = 0; q_ < 2; ++q_)                          \
        async_ld16(pB[hh][q_] + (size_t)(t) * 64,                             \
                   smem + (bufb) + 32768 + (hh) * 16384 + q_ * 8192 + woff);  \
  }

#define LOAD_AF(bb, ihalf, kf)                                                \
  _Pragma("unroll") for (int i_ = 0; i_ < 4; ++i_)                            \
      af[i_] = *(const h8*)(smem + (bb) + (a_rd ^ ((kf) << 6)) +              \
                            (ihalf) * 8192 + i_ * 2048);

#define MFMA16(ih, bfb)                                                       \
  __builtin_amdgcn_s_setprio(1);                                              \
  _Pragma("unroll") for (int i_ = 0; i_ < 4; ++i_)                            \
      _Pragma("unroll") for (int j_ = 0; j_ < 4; ++j_)                        \
          acc[(ih) * 4 + i_][j_] = __builtin_amdgcn_mfma_f32_16x16x32_f16(    \
              af[i_], bf[(bfb) + j_], acc[(ih) * 4 + i_][j_], 0, 0, 0);       \
  __builtin_amdgcn_s_setprio(0);

#define BAR  MEMFENCE; __builtin_amdgcn_s_barrier(); MEMFENCE

// MODE: 0 = f16 out + bias; 1 = fused softmax-merge (reads Et/El, writes Mg);
//       2 = fp32 out + bias.
// Tile 256x256, BK=64, 8 waves (2 row x 4 col), per-wave 128x64 output.
// LDS 128KB = 2 buffers x (A 32KB + B 32KB); element (row,k) at byte
// row*128 + ((k>>3) ^ (row&7))*16 + (k&7)*2  (pre-swizzled global source,
// linear LDS dest; fragment reads 2 lanes/bank-group = conflict-free).
template<int NT, int MODE>
__launch_bounds__(512, 2)
__global__ void gemm256(const _Float16* __restrict__ A, int lda,
                        const _Float16* __restrict__ B, int ldb,
                        const float* __restrict__ bias,
                        const _Float16* __restrict__ Et,
                        const _Float16* __restrict__ El,
                        _Float16* __restrict__ C16,
                        float* __restrict__ C32) {
  __shared__ char smem[131072];

  // XCD-aware swizzle (512 % 8 == 0 -> bijective).
  const int b  = blockIdx.x;
  const int bp = ((b & 7) << 6) | (b >> 3);
  const int row0 = (bp & 127) << 8;
  const int col0 = (bp >> 7) << 8;

  const int tid  = threadIdx.x;
  const int w    = tid >> 6;
  const int lane = tid & 63;
  const int quad = lane >> 4;
  const int l16  = lane & 15;
  const int wr   = w >> 2;            // 0..1
  const int wc   = w & 3;             // 0..3

  // staging sources: thread covers row grow of each 64-row quarter,
  // global k-slot pre-swizzled so linear LDS dest yields swizzled layout.
  const int grow = (w << 3) + (lane >> 3);             // 0..63
  const int ss   = (((lane & 7) ^ (lane >> 3)) << 3);  // halves
  const _Float16* pA[2][2];
  const _Float16* pB[2][2];
#pragma unroll
  for (int h = 0; h < 2; ++h)
#pragma unroll
    for (int q = 0; q < 2; ++q) {
      pA[h][q] = A + (size_t)(row0 + h * 128 + q * 64 + grow) * (size_t)lda + ss;
      pB[h][q] = B + (size_t)(col0 + h * 128 + q * 64 + grow) * (size_t)ldb + ss;
    }
  const int woff = w << 10;

  // fragment-read byte offsets (kf toggles bit 6 via XOR)
  const uint32_t sw   = (uint32_t)((quad ^ (l16 & 7)) << 4);
  const uint32_t a_rd = (uint32_t)(((wr << 7) + l16) << 7) + sw;
  const uint32_t b_rd = 32768u + (uint32_t)(((wc << 6) + l16) << 7) + sw;

  f4 acc[8][4];
  const f4 z = {0.f, 0.f, 0.f, 0.f};
#pragma unroll
  for (int i = 0; i < 8; ++i)
#pragma unroll
    for (int j = 0; j < 4; ++j) acc[i][j] = z;

  // ---- prologue: tile0 full (buf0) + B halves of tile1 (buf1) ----
  STAGE_A(0, 0, 0); STAGE_A(1, 0, 0);
  STAGE_B(0, 0, 0); STAGE_B(1, 0, 0);
  STAGE_B(0, 1, 65536); STAGE_B(1, 1, 65536);
  asm volatile("s_waitcnt vmcnt(4)" ::: "memory");   // tile0 landed
  BAR;

  uint32_t cur = 0;
  for (int t = 0; t < NT; ++t) {
    const uint32_t nxt = cur ^ 65536u;
    const int tA = (t + 1 < NT) ? t + 1 : NT - 1;    // dummy re-stage at tail
    const int tB = (t + 2 < NT) ? t + 2 : NT - 1;

    h8 af[4], bf[8];
    // ---- phase 0: af(i0-3,kf0) + ALL bf (12 reads) | stage A-h0(t+1) ----
    LOAD_AF(cur, 0, 0);
#pragma unroll
    for (int j = 0; j < 4; ++j) bf[j]     = *(const h8*)(smem + cur + b_rd + j * 2048);
#pragma unroll
    for (int j = 0; j < 4; ++j) bf[4 + j] = *(const h8*)(smem + cur + (b_rd ^ 64u) + j * 2048);
    STAGE_A(0, tA, nxt);
    BAR;
    MFMA16(0, 0);
    BAR;

    // ---- phase 1: af(i4-7,kf0) | stage A-h1(t+1) ----
    LOAD_AF(cur, 1, 0);
    STAGE_A(1, tA, nxt);
    BAR;
    MFMA16(1, 0);
    BAR;

    // ---- phase 2: af(i0-3,kf1) | stage B-h0(t+2) into cur (slot free) ----
    LOAD_AF(cur, 0, 1);
    STAGE_B(0, tB, cur);
    BAR;
    MFMA16(0, 4);
    BAR;

    // ---- phase 3: af(i4-7,kf1) | stage B-h1(t+2) | vmcnt(4) ----
    LOAD_AF(cur, 1, 1);
    STAGE_B(1, tB, cur);
    asm volatile("s_waitcnt vmcnt(4)" ::: "memory");  // tile t+1 fully landed
    BAR;
    MFMA16(1, 4);
    BAR;

    cur = nxt;
  }
  asm volatile("s_waitcnt vmcnt(0)" ::: "memory");    // drain dummy stages

  // ---- epilogue ----
  // C frag layout: col = l16, row = quad*4 + r; acc[i] rows = wr*128 + i*16.
  const int cbase  = col0 + (wc << 6);
  const int rbase0 = row0 + (wr << 7) + (quad << 2);

  if constexpr (MODE == 0) {
    float bj[4];
#pragma unroll
    for (int j = 0; j < 4; ++j) bj[j] = bias[cbase + j * 16 + l16];
#pragma unroll
    for (int i = 0; i < 8; ++i)
#pragma unroll
      for (int j = 0; j < 4; ++j) {
        const size_t co = (size_t)(cbase + j * 16 + l16);
#pragma unroll
        for (int r = 0; r < 4; ++r)
          C16[(size_t)(rbase0 + i * 16 + r) * 1024 + co] =
              (_Float16)(acc[i][j][r] + bj[j]);
      }
  } else if constexpr (MODE == 2) {
    float bj[4];
#pragma unroll
    for (int j = 0; j < 4; ++j) bj[j] = bias[cbase + j * 16 + l16];
#pragma unroll
    for (int i = 0; i < 8; ++i)
#pragma unroll
      for (int j = 0; j < 4; ++j) {
        const size_t co = (size_t)(cbase + j * 16 + l16);
#pragma unroll
        for (int r = 0; r < 4; ++r)
          C32[(size_t)(rbase0 + i * 16 + r) * 1024 + co] = acc[i][j][r] + bj[j];
      }
  } else {
    // fused softmax-merge: wave's 64 cols == exactly one head group.
    float bvj[4];
#pragma unroll
    for (int j = 0; j < 4; ++j) bvj[j] = bias[cbase + j * 16 + l16];
#pragma unroll
    for (int i = 0; i < 8; ++i) {
      float pv[4][4];
      float s[4] = {0.f, 0.f, 0.f, 0.f};
      const int rb = rbase0 + i * 16;
#pragma unroll
      for (int j = 0; j < 4; ++j) {
        const size_t co = (size_t)(cbase + j * 16 + l16);
#pragma unroll
        for (int r = 0; r < 4; ++r) {
          const size_t off = (size_t)(rb + r) * 1024 + co;
          const float tv = (float)Et[off];   // bias already folded in
          const float lv = (float)El[off];
          const float p  = __expf(tv * lv);
          pv[j][r] = p * (acc[i][j][r] + bvj[j]);
          s[r] += p;
        }
      }
#pragma unroll
      for (int r = 0; r < 4; ++r) {
        s[r] += __shfl_xor(s[r], 1);
        s[r] += __shfl_xor(s[r], 2);
        s[r] += __shfl_xor(s[r], 4);
        s[r] += __shfl_xor(s[r], 8);
        s[r] = 1.0f / s[r];
      }
#pragma unroll
      for (int j = 0; j < 4; ++j) {
        const size_t co = (size_t)(cbase + j * 16 + l16);
#pragma unroll
        for (int r = 0; r < 4; ++r)
          C16[(size_t)(rb + r) * 1024 + co] = (_Float16)(pv[j][r] * s[r]);
      }
    }
  }
}

// ---------------------------------------------------------------------------
// Prep kernels (unchanged)
// ---------------------------------------------------------------------------
__global__ void cvt_inputs(const float4* __restrict__ t,
                           const float4* __restrict__ l,
                           h4* __restrict__ X) {
  const size_t idx = (size_t)blockIdx.x * 256 + threadIdx.x;  // N*1024/4
  const size_t n  = idx >> 8;
  const size_t k4 = idx & 255;
  const float4 a = t[idx];
  const float4 b = l[idx];
  h4 ha, hb;
  ha[0] = (_Float16)a.x; ha[1] = (_Float16)a.y;
  ha[2] = (_Float16)a.z; ha[3] = (_Float16)a.w;
  hb[0] = (_Float16)b.x; hb[1] = (_Float16)b.y;
  hb[2] = (_Float16)b.z; hb[3] = (_Float16)b.w;
  X[n * 512 + k4]       = ha;
  X[n * 512 + 256 + k4] = hb;
}

__global__ void cvt_flat(const float4* __restrict__ W, h4* __restrict__ Wp) {
  const int idx = blockIdx.x * 256 + threadIdx.x;
  const float4 v = W[idx];
  h4 hv;
  hv[0] = (_Float16)v.x; hv[1] = (_Float16)v.y;
  hv[2] = (_Float16)v.z; hv[3] = (_Float16)v.w;
  Wp[idx] = hv;
}

// Wo with K-dim permuted to match Mg's column order c = h*64+o
__global__ void cvt_wo_perm(const float* __restrict__ Wo,
                            _Float16* __restrict__ Wp) {
  const int idx = blockIdx.x * 256 + threadIdx.x;  // 1M
  const int j = idx >> 10, c = idx & 1023;
  const int k = (c & 63) * 16 + (c >> 6);
  Wp[idx] = (_Float16)Wo[j * 1024 + k];
}

// ---------------------------------------------------------------------------
// Launch. ws (~212 MB):  X16 134MB | Wt16 2MB | Wl16 2MB | Wv16 4MB |
//                        Wo16 2MB  | Mg 67MB
// d_out doubles as f16 scratch for Et/El (2 x 67MB = exactly out_size);
// consumed by the V kernel before the final GEMM overwrites d_out.
// ---------------------------------------------------------------------------
extern "C" void kernel_launch(void* const* d_in, const int* in_sizes, int n_in,
                              void* d_out, int out_size, void* d_ws, size_t ws_size,
                              hipStream_t stream) {
  const float* t_inp = (const float*)d_in[0];
  const float* l_inp = (const float*)d_in[1];
  const float* Wt = (const float*)d_in[2];
  const float* bt = (const float*)d_in[3];
  const float* Wl = (const float*)d_in[4];
  const float* bl = (const float*)d_in[5];
  const float* Wv = (const float*)d_in[6];
  const float* bv = (const float*)d_in[7];
  const float* Wo = (const float*)d_in[8];
  const float* bo = (const float*)d_in[9];
  float* out = (float*)d_out;

  char* ws = (char*)d_ws;
  _Float16* X16  = (_Float16*)ws;
  _Float16* Wt16 = (_Float16*)(ws + 134217728ull);
  _Float16* Wl16 = Wt16 + 1024 * 1024;
  _Float16* Wv16 = Wl16 + 1024 * 1024;
  _Float16* Wo16 = Wv16 + 1024 * 2048;
  _Float16* Mg   = Wo16 + 1024 * 1024;

  _Float16* Et16 = (_Float16*)d_out;            // scratch: 67MB
  _Float16* El16 = Et16 + (size_t)NROWS * 1024; // scratch: 67MB

  cvt_inputs<<<dim3(32768), dim3(256), 0, stream>>>(
      (const float4*)t_inp, (const float4*)l_inp, (h4*)X16);
  cvt_flat<<<dim3(1024), dim3(256), 0, stream>>>((const float4*)Wt, (h4*)Wt16);
  cvt_flat<<<dim3(1024), dim3(256), 0, stream>>>((const float4*)Wl, (h4*)Wl16);
  cvt_flat<<<dim3(2048), dim3(256), 0, stream>>>((const float4*)Wv, (h4*)Wv16);
  cvt_wo_perm<<<dim3(4096), dim3(256), 0, stream>>>(Wo, Wo16);

  // Et = X_t * Wt^T + bt   (f16, into d_out scratch)   K=1024 -> NT=16
  gemm256<16, 0><<<dim3(512), dim3(512), 0, stream>>>(
      X16, 2048, Wt16, 1024, bt, nullptr, nullptr, Et16, nullptr);
  // El = X_l * Wl^T + bl
  gemm256<16, 0><<<dim3(512), dim3(512), 0, stream>>>(
      X16 + 1024, 2048, Wl16, 1024, bl, nullptr, nullptr, El16, nullptr);
  // V GEMM + fused softmax-merge -> Mg                 K=2048 -> NT=32
  gemm256<32, 1><<<dim3(512), dim3(512), 0, stream>>>(
      X16, 2048, Wv16, 2048, bv, Et16, El16, Mg, nullptr);
  // final projection (fp32 out + bias)                 K=1024 -> NT=16
  gemm256<16, 2><<<dim3(512), dim3(512), 0, stream>>>(
      Mg, 1024, Wo16, 1024, bo, nullptr, nullptr, nullptr, out);
}

// Round 5
// 732.992 us; speedup vs baseline: 1.0943x; 1.0221x over previous
//
#include <hip/hip_runtime.h>
#include <stdint.h>
#include <stddef.h>

// ---------------------------------------------------------------------------
// Round 7: race-fixed 2-cluster schedule (32 MFMA per cluster, BK=64).
// Fix vs round 6: bf for BOTH k-halves front-loaded in cluster 0, and an
// explicit lgkmcnt(0) before cluster-0's ending barrier guarantees all bf
// reads are in registers before any wave issues STAGE_B into cur's B-slot
// (round 6 read cur-B and DMA-overwrote cur-B in the same barrier window).
// 4 barriers/K-tile, counted vmcnt(4) once per K-tile (never drained).
// Conflict-free swizzled LDS (measured 0 conflicts) unchanged.
// Used 4x:  Et = X_t*Wt^T+bt   (f16 out, scratch in d_out)
//           El = X_l*Wl^T+bl   (f16 out, scratch in d_out)
//           V-GEMM + fused softmax-merge epilogue -> Mg (f16, ws)
//           final projection (fp32 out + bias)
// ---------------------------------------------------------------------------

typedef _Float16 h8 __attribute__((ext_vector_type(8)));
typedef _Float16 h4 __attribute__((ext_vector_type(4)));
typedef float    f4 __attribute__((ext_vector_type(4)));

#define NROWS 32768

__device__ __forceinline__ void async_ld16(const void* g, void* s) {
  __builtin_amdgcn_global_load_lds(
      (const __attribute__((address_space(1))) uint32_t*)g,
      (__attribute__((address_space(3))) uint32_t*)s, 16, 0, 0);
}

#define MEMFENCE asm volatile("" ::: "memory")

// Stage one A half-tile (rows hh*128..+127, K-tile t) into buffer at bufb.
#define STAGE_A(hh, t, bufb)                                                  \
  {                                                                           \
    _Pragma("unroll") for (int q_ = 0; q_ < 2; ++q_)                          \
        async_ld16(pA[hh][q_] + (size_t)(t) * 64,                             \
                   smem + (bufb) + (hh) * 16384 + q_ * 8192 + woff);          \
  }
#define STAGE_B(hh, t, bufb)                                                  \
  {                                                                           \
    _Pragma("unroll") for (int q_ = 0; q_ < 2; ++q_)                          \
        async_ld16(pB[hh][q_] + (size_t)(t) * 64,                             \
                   smem + (bufb) + 32768 + (hh) * 16384 + q_ * 8192 + woff);  \
  }

// Load ALL 8 af fragments (both i-halves) for k-half kf from buffer bb.
#define LOAD_AF8(bb, kf)                                                      \
  _Pragma("unroll") for (int ih_ = 0; ih_ < 2; ++ih_)                         \
      _Pragma("unroll") for (int i_ = 0; i_ < 4; ++i_)                        \
          af[ih_ * 4 + i_] = *(const h8*)(smem + (bb) +                       \
              (a_rd ^ ((kf) << 6)) + ih_ * 8192 + i_ * 2048);

// Load ALL 8 bf fragments (both k-halves) from buffer bb.
#define LOAD_BF8(bb)                                                          \
  _Pragma("unroll") for (int j_ = 0; j_ < 4; ++j_)                            \
      bf[j_] = *(const h8*)(smem + (bb) + b_rd + j_ * 2048);                  \
  _Pragma("unroll") for (int j_ = 0; j_ < 4; ++j_)                            \
      bf[4 + j_] = *(const h8*)(smem + (bb) + (b_rd ^ 64u) + j_ * 2048);

// 32 MFMA: all 8 i-frags x 4 j-frags for one k-half (bf base bfb).
#define MFMA32(bfb)                                                           \
  __builtin_amdgcn_s_setprio(1);                                              \
  _Pragma("unroll") for (int i_ = 0; i_ < 8; ++i_)                            \
      _Pragma("unroll") for (int j_ = 0; j_ < 4; ++j_)                        \
          acc[i_][j_] = __builtin_amdgcn_mfma_f32_16x16x32_f16(               \
              af[i_], bf[(bfb) + j_], acc[i_][j_], 0, 0, 0);                  \
  __builtin_amdgcn_s_setprio(0);

#define BAR  MEMFENCE; __builtin_amdgcn_s_barrier(); MEMFENCE

// MODE: 0 = f16 out + bias; 1 = fused softmax-merge (reads Et/El, writes Mg);
//       2 = fp32 out + bias.
// Tile 256x256, BK=64, 8 waves (2 row x 4 col), per-wave 128x64 output.
// LDS 128KB = 2 buffers x (A 32KB + B 32KB); element (row,k) at byte
// row*128 + ((k>>3) ^ (row&7))*16 + (k&7)*2  (pre-swizzled global source,
// linear LDS dest; fragment reads 2 lanes/bank-group = conflict-free).
template<int NT, int MODE>
__launch_bounds__(512, 2)
__global__ void gemm256(const _Float16* __restrict__ A, int lda,
                        const _Float16* __restrict__ B, int ldb,
                        const float* __restrict__ bias,
                        const _Float16* __restrict__ Et,
                        const _Float16* __restrict__ El,
                        _Float16* __restrict__ C16,
                        float* __restrict__ C32) {
  __shared__ char smem[131072];

  // XCD-aware swizzle (512 % 8 == 0 -> bijective).
  const int b  = blockIdx.x;
  const int bp = ((b & 7) << 6) | (b >> 3);
  const int row0 = (bp & 127) << 8;
  const int col0 = (bp >> 7) << 8;

  const int tid  = threadIdx.x;
  const int w    = tid >> 6;
  const int lane = tid & 63;
  const int quad = lane >> 4;
  const int l16  = lane & 15;
  const int wr   = w >> 2;            // 0..1
  const int wc   = w & 3;             // 0..3

  // staging sources: thread covers row grow of each 64-row quarter,
  // global k-slot pre-swizzled so linear LDS dest yields swizzled layout.
  const int grow = (w << 3) + (lane >> 3);             // 0..63
  const int ss   = (((lane & 7) ^ (lane >> 3)) << 3);  // halves
  const _Float16* pA[2][2];
  const _Float16* pB[2][2];
#pragma unroll
  for (int h = 0; h < 2; ++h)
#pragma unroll
    for (int q = 0; q < 2; ++q) {
      pA[h][q] = A + (size_t)(row0 + h * 128 + q * 64 + grow) * (size_t)lda + ss;
      pB[h][q] = B + (size_t)(col0 + h * 128 + q * 64 + grow) * (size_t)ldb + ss;
    }
  const int woff = w << 10;

  // fragment-read byte offsets (kf toggles bit 6 via XOR)
  const uint32_t sw   = (uint32_t)((quad ^ (l16 & 7)) << 4);
  const uint32_t a_rd = (uint32_t)(((wr << 7) + l16) << 7) + sw;
  const uint32_t b_rd = 32768u + (uint32_t)(((wc << 6) + l16) << 7) + sw;

  f4 acc[8][4];
  const f4 z = {0.f, 0.f, 0.f, 0.f};
#pragma unroll
  for (int i = 0; i < 8; ++i)
#pragma unroll
    for (int j = 0; j < 4; ++j) acc[i][j] = z;

  // ---- prologue: tile0 full (buf0) + B halves of tile1 (buf1) ----
  STAGE_A(0, 0, 0); STAGE_A(1, 0, 0);
  STAGE_B(0, 0, 0); STAGE_B(1, 0, 0);
  STAGE_B(0, 1, 65536); STAGE_B(1, 1, 65536);
  asm volatile("s_waitcnt vmcnt(4)" ::: "memory");   // tile0 landed
  BAR;

  uint32_t cur = 0;
  for (int t = 0; t < NT; ++t) {
    const uint32_t nxt = cur ^ 65536u;
    const int tA = (t + 1 < NT) ? t + 1 : NT - 1;    // dummy re-stage at tail
    const int tB = (t + 2 < NT) ? t + 2 : NT - 1;

    h8 af[8], bf[8];
    // ---- cluster 0 (k-half 0): 16 reads (af k0 + bf BOTH halves) |
    //      stage A(t+1) -> nxt | 32 MFMA | lgkm drain | barrier ----
    LOAD_AF8(cur, 0);
    LOAD_BF8(cur);
    STAGE_A(0, tA, nxt);
    STAGE_A(1, tA, nxt);
    BAR;
    MFMA32(0);
    // all 16 ds_reads (incl. bf[4..7]) must be in registers before any wave
    // crosses the next barrier and DMA-overwrites cur's B-slot below.
    asm volatile("s_waitcnt lgkmcnt(0)" ::: "memory");
    BAR;

    // ---- cluster 1 (k-half 1): 8 af reads | stage B(t+2) -> cur (B-slot
    //      free: bf already in regs) | vmcnt(4) | 32 MFMA ----
    LOAD_AF8(cur, 1);
    STAGE_B(0, tB, cur);
    STAGE_B(1, tB, cur);
    asm volatile("s_waitcnt vmcnt(4)" ::: "memory");  // tile t+1 fully landed
    BAR;
    MFMA32(4);
    BAR;

    cur = nxt;
  }
  asm volatile("s_waitcnt vmcnt(0)" ::: "memory");    // drain dummy stages

  // ---- epilogue ----
  // C frag layout: col = l16, row = quad*4 + r; acc[i] rows = wr*128 + i*16.
  const int cbase  = col0 + (wc << 6);
  const int rbase0 = row0 + (wr << 7) + (quad << 2);

  if constexpr (MODE == 0) {
    float bj[4];
#pragma unroll
    for (int j = 0; j < 4; ++j) bj[j] = bias[cbase + j * 16 + l16];
#pragma unroll
    for (int i = 0; i < 8; ++i)
#pragma unroll
      for (int j = 0; j < 4; ++j) {
        const size_t co = (size_t)(cbase + j * 16 + l16);
#pragma unroll
        for (int r = 0; r < 4; ++r)
          C16[(size_t)(rbase0 + i * 16 + r) * 1024 + co] =
              (_Float16)(acc[i][j][r] + bj[j]);
      }
  } else if constexpr (MODE == 2) {
    float bj[4];
#pragma unroll
    for (int j = 0; j < 4; ++j) bj[j] = bias[cbase + j * 16 + l16];
#pragma unroll
    for (int i = 0; i < 8; ++i)
#pragma unroll
      for (int j = 0; j < 4; ++j) {
        const size_t co = (size_t)(cbase + j * 16 + l16);
#pragma unroll
        for (int r = 0; r < 4; ++r)
          C32[(size_t)(rbase0 + i * 16 + r) * 1024 + co] = acc[i][j][r] + bj[j];
      }
  } else {
    // fused softmax-merge: wave's 64 cols == exactly one head group.
    float bvj[4];
#pragma unroll
    for (int j = 0; j < 4; ++j) bvj[j] = bias[cbase + j * 16 + l16];
#pragma unroll
    for (int i = 0; i < 8; ++i) {
      float pv[4][4];
      float s[4] = {0.f, 0.f, 0.f, 0.f};
      const int rb = rbase0 + i * 16;
#pragma unroll
      for (int j = 0; j < 4; ++j) {
        const size_t co = (size_t)(cbase + j * 16 + l16);
#pragma unroll
        for (int r = 0; r < 4; ++r) {
          const size_t off = (size_t)(rb + r) * 1024 + co;
          const float tv = (float)Et[off];   // bias already folded in
          const float lv = (float)El[off];
          const float p  = __expf(tv * lv);
          pv[j][r] = p * (acc[i][j][r] + bvj[j]);
          s[r] += p;
        }
      }
#pragma unroll
      for (int r = 0; r < 4; ++r) {
        s[r] += __shfl_xor(s[r], 1);
        s[r] += __shfl_xor(s[r], 2);
        s[r] += __shfl_xor(s[r], 4);
        s[r] += __shfl_xor(s[r], 8);
        s[r] = 1.0f / s[r];
      }
#pragma unroll
      for (int j = 0; j < 4; ++j) {
        const size_t co = (size_t)(cbase + j * 16 + l16);
#pragma unroll
        for (int r = 0; r < 4; ++r)
          C16[(size_t)(rb + r) * 1024 + co] = (_Float16)(pv[j][r] * s[r]);
      }
    }
  }
}

// ---------------------------------------------------------------------------
// Prep kernels (unchanged)
// ---------------------------------------------------------------------------
__global__ void cvt_inputs(const float4* __restrict__ t,
                           const float4* __restrict__ l,
                           h4* __restrict__ X) {
  const size_t idx = (size_t)blockIdx.x * 256 + threadIdx.x;  // N*1024/4
  const size_t n  = idx >> 8;
  const size_t k4 = idx & 255;
  const float4 a = t[idx];
  const float4 b = l[idx];
  h4 ha, hb;
  ha[0] = (_Float16)a.x; ha[1] = (_Float16)a.y;
  ha[2] = (_Float16)a.z; ha[3] = (_Float16)a.w;
  hb[0] = (_Float16)b.x; hb[1] = (_Float16)b.y;
  hb[2] = (_Float16)b.z; hb[3] = (_Float16)b.w;
  X[n * 512 + k4]       = ha;
  X[n * 512 + 256 + k4] = hb;
}

__global__ void cvt_flat(const float4* __restrict__ W, h4* __restrict__ Wp) {
  const int idx = blockIdx.x * 256 + threadIdx.x;
  const float4 v = W[idx];
  h4 hv;
  hv[0] = (_Float16)v.x; hv[1] = (_Float16)v.y;
  hv[2] = (_Float16)v.z; hv[3] = (_Float16)v.w;
  Wp[idx] = hv;
}

// Wo with K-dim permuted to match Mg's column order c = h*64+o
__global__ void cvt_wo_perm(const float* __restrict__ Wo,
                            _Float16* __restrict__ Wp) {
  const int idx = blockIdx.x * 256 + threadIdx.x;  // 1M
  const int j = idx >> 10, c = idx & 1023;
  const int k = (c & 63) * 16 + (c >> 6);
  Wp[idx] = (_Float16)Wo[j * 1024 + k];
}

// ---------------------------------------------------------------------------
// Launch. ws (~212 MB):  X16 134MB | Wt16 2MB | Wl16 2MB | Wv16 4MB |
//                        Wo16 2MB  | Mg 67MB
// d_out doubles as f16 scratch for Et/El (2 x 67MB = exactly out_size);
// consumed by the V kernel before the final GEMM overwrites d_out.
// ---------------------------------------------------------------------------
extern "C" void kernel_launch(void* const* d_in, const int* in_sizes, int n_in,
                              void* d_out, int out_size, void* d_ws, size_t ws_size,
                              hipStream_t stream) {
  const float* t_inp = (const float*)d_in[0];
  const float* l_inp = (const float*)d_in[1];
  const float* Wt = (const float*)d_in[2];
  const float* bt = (const float*)d_in[3];
  const float* Wl = (const float*)d_in[4];
  const float* bl = (const float*)d_in[5];
  const float* Wv = (const float*)d_in[6];
  const float* bv = (const float*)d_in[7];
  const float* Wo = (const float*)d_in[8];
  const float* bo = (const float*)d_in[9];
  float* out = (float*)d_out;

  char* ws = (char*)d_ws;
  _Float16* X16  = (_Float16*)ws;
  _Float16* Wt16 = (_Float16*)(ws + 134217728ull);
  _Float16* Wl16 = Wt16 + 1024 * 1024;
  _Float16* Wv16 = Wl16 + 1024 * 1024;
  _Float16* Wo16 = Wv16 + 1024 * 2048;
  _Float16* Mg   = Wo16 + 1024 * 1024;

  _Float16* Et16 = (_Float16*)d_out;            // scratch: 67MB
  _Float16* El16 = Et16 + (size_t)NROWS * 1024; // scratch: 67MB

  cvt_inputs<<<dim3(32768), dim3(256), 0, stream>>>(
      (const float4*)t_inp, (const float4*)l_inp, (h4*)X16);
  cvt_flat<<<dim3(1024), dim3(256), 0, stream>>>((const float4*)Wt, (h4*)Wt16);
  cvt_flat<<<dim3(1024), dim3(256), 0, stream>>>((const float4*)Wl, (h4*)Wl16);
  cvt_flat<<<dim3(2048), dim3(256), 0, stream>>>((const float4*)Wv, (h4*)Wv16);
  cvt_wo_perm<<<dim3(4096), dim3(256), 0, stream>>>(Wo, Wo16);

  // Et = X_t * Wt^T + bt   (f16, into d_out scratch)   K=1024 -> NT=16
  gemm256<16, 0><<<dim3(512), dim3(512), 0, stream>>>(
      X16, 2048, Wt16, 1024, bt, nullptr, nullptr, Et16, nullptr);
  // El = X_l * Wl^T + bl
  gemm256<16, 0><<<dim3(512), dim3(512), 0, stream>>>(
      X16 + 1024, 2048, Wl16, 1024, bl, nullptr, nullptr, El16, nullptr);
  // V GEMM + fused softmax-merge -> Mg                 K=2048 -> NT=32
  gemm256<32, 1><<<dim3(512), dim3(512), 0, stream>>>(
      X16, 2048, Wv16, 2048, bv, Et16, El16, Mg, nullptr);
  // final projection (fp32 out + bias)                 K=1024 -> NT=16
  gemm256<16, 2><<<dim3(512), dim3(512), 0, stream>>>(
      Mg, 1024, Wo16, 1024, bo, nullptr, nullptr, nullptr, out);
}